// Round 4
// baseline (447.607 us; speedup 1.0000x reference)
//
#include <hip/hip_runtime.h>
#include <hip/hip_bf16.h>

#define N_NODES 8192
#define N_EDGES 262144
// F_IN=512, H1=256, H2=128 (x2 fused), H3=64, OUT6=6

typedef __attribute__((ext_vector_type(8))) short short8;
typedef __attribute__((ext_vector_type(4))) float f32x4;

__device__ __forceinline__ unsigned short f2bf(float f) {
    unsigned int u = __float_as_uint(f);
    u = (u + 0x7fffu + ((u >> 16) & 1u)) >> 16;  // RNE
    return (unsigned short)u;
}
__device__ __forceinline__ float bf2f(unsigned short h) {
    return __uint_as_float((unsigned int)h << 16);
}

// ---------------- CSR build ----------------
__global__ void k_scan(const int* __restrict__ counts, int* __restrict__ offs) {
    __shared__ int part[1024];
    int t = threadIdx.x;
    int base = t * 8;
    int loc[8];
    int s = 0;
#pragma unroll
    for (int i = 0; i < 8; i++) { loc[i] = s; s += counts[base + i]; }
    part[t] = s;
    __syncthreads();
    for (int off = 1; off < 1024; off <<= 1) {
        int v = (t >= off) ? part[t - off] : 0;
        __syncthreads();
        part[t] += v;
        __syncthreads();
    }
    int prev = (t == 0) ? 0 : part[t - 1];
#pragma unroll
    for (int i = 0; i < 8; i++) offs[base + i] = prev + loc[i];
    if (t == 1023) offs[N_NODES] = part[1023];
}

__global__ void k_scatter(const int* __restrict__ rows, const int* __restrict__ colsIn,
                          const float* __restrict__ valsIn, const int* __restrict__ offs,
                          int* __restrict__ cursor, int* __restrict__ colsOut,
                          float* __restrict__ valsOut) {
    int e = blockIdx.x * 256 + threadIdx.x;
    if (e >= N_EDGES) return;
    int r = rows[e];
    int p = atomicAdd(&cursor[r], 1);
    int idx = offs[r] + p;
    colsOut[idx] = colsIn[e];
    valsOut[idx] = valsIn[e];
}

// ---------------- fused prep: hist + converts + weight folds ----------------
// blocks [0,1024): hist; [1024,5120): x->bf16; [5120,5632): W1^T bf16;
// [5632,5760): W23dt = ([W2|W3] @ blockdiag fold with dense_W)^T bf16 [128][256]
__global__ void k_prep(const int* __restrict__ rows, int* __restrict__ counts,
                       const float* __restrict__ x, ushort* __restrict__ xh,
                       const float* __restrict__ W1, ushort* __restrict__ W1t,
                       const float* __restrict__ W2, const float* __restrict__ W3,
                       const float* __restrict__ dW, ushort* __restrict__ W23dt) {
    int b = blockIdx.x, t = threadIdx.x;
    if (b < 1024) {
        atomicAdd(&counts[rows[b * 256 + t]], 1);
    } else if (b < 5120) {
        int i = (b - 1024) * 256 + t;  // over 1048576 float4
        float4 v = ((const float4*)x)[i];
        ((ushort4*)xh)[i] = make_ushort4(f2bf(v.x), f2bf(v.y), f2bf(v.z), f2bf(v.w));
    } else if (b < 5632) {
        int i = (b - 5120) * 256 + t;  // over 131072, i = k*256+n
        int k = i >> 8, n = i & 255;
        W1t[n * 512 + k] = f2bf(W1[i]);
    } else {
        // W23dt[n][k] = sum_j Wsrc[k][j] * dW[j][n&63], fp32 accumulate
        int i = (b - 5632) * 256 + t;  // over 32768, i = n*256+k
        int n = i >> 8, k = i & 255;
        const float* src = (n < 64) ? W2 : W3;
        int nn = n & 63;
        float acc = 0.f;
        for (int j = 0; j < 128; j++)
            acc += src[k * 128 + j] * dW[j * 64 + nn];
        W23dt[i] = f2bf(acc);
    }
}

// ---------------- bf16 MFMA GEMM: C[M,ldc] = A[M,K] @ Bt[N,K]^T, bf16 out ----------------
// block = 128 thr = 2 waves stacked on M; block tile 128x64; wave tile 64x64.
__global__ __launch_bounds__(128) void k_gemm_mfma(const ushort* __restrict__ A,
                                                   const ushort* __restrict__ Bt,
                                                   ushort* __restrict__ C,
                                                   int K, int ldc) {
    int t = threadIdx.x;
    int lane = t & 63;
    int w = t >> 6;
    int I = blockIdx.y * 128 + w * 64;
    int J = blockIdx.x * 64;
    int r = lane & 15;
    int koff = (lane >> 4) * 8;
    const ushort* Ab = A + (size_t)(I + r) * K + koff;
    const ushort* Bb = Bt + (size_t)(J + r) * K + koff;
    size_t rs = (size_t)16 * K;

    short8 a0[4], b0[4], a1[4], b1[4];
#pragma unroll
    for (int m = 0; m < 4; m++) {
        a0[m] = *(const short8*)(Ab + m * rs);
        b0[m] = *(const short8*)(Bb + m * rs);
    }
    f32x4 acc[4][4];
#pragma unroll
    for (int m = 0; m < 4; m++)
#pragma unroll
        for (int n = 0; n < 4; n++) acc[m][n] = (f32x4){0.f, 0.f, 0.f, 0.f};

    int nk = K >> 5;  // K=512 -> 16, K=256 -> 8 (even)
    for (int kt = 0; kt < nk; kt += 2) {
        int o1 = (kt + 1) << 5;
#pragma unroll
        for (int m = 0; m < 4; m++) {
            a1[m] = *(const short8*)(Ab + m * rs + o1);
            b1[m] = *(const short8*)(Bb + m * rs + o1);
        }
#pragma unroll
        for (int m = 0; m < 4; m++)
#pragma unroll
            for (int n = 0; n < 4; n++)
                acc[m][n] = __builtin_amdgcn_mfma_f32_16x16x32_bf16(a0[m], b0[n], acc[m][n], 0, 0, 0);
        if (kt + 2 < nk) {
            int o2 = (kt + 2) << 5;
#pragma unroll
            for (int m = 0; m < 4; m++) {
                a0[m] = *(const short8*)(Ab + m * rs + o2);
                b0[m] = *(const short8*)(Bb + m * rs + o2);
            }
        }
#pragma unroll
        for (int m = 0; m < 4; m++)
#pragma unroll
            for (int n = 0; n < 4; n++)
                acc[m][n] = __builtin_amdgcn_mfma_f32_16x16x32_bf16(a1[m], b1[n], acc[m][n], 0, 0, 0);
    }

    // C/D layout: col = lane&15, row = (lane>>4)*4 + reg   [m89-verified]
    int crow = (lane >> 4) * 4;
    int ccol = lane & 15;
#pragma unroll
    for (int m = 0; m < 4; m++)
#pragma unroll
        for (int rg = 0; rg < 4; rg++) {
            size_t row = (size_t)(I + m * 16 + crow + rg);
#pragma unroll
            for (int n = 0; n < 4; n++)
                C[row * ldc + J + n * 16 + ccol] = f2bf(acc[m][n][rg]);
        }
}

// ---------------- SpMM (CSR), D=256 bf16 in/out, relu: one row per WAVE ----------------
__global__ __launch_bounds__(256) void k_spmm_v2(const int* __restrict__ offs,
                                                 const int* __restrict__ cols,
                                                 const float* __restrict__ vals,
                                                 const ushort* __restrict__ in,
                                                 ushort* __restrict__ out) {
    int w = threadIdx.x >> 6;
    int lane = threadIdx.x & 63;
    int row = blockIdx.x * 4 + w;
    int colo = lane * 4;
    int i = offs[row], e = offs[row + 1];
    float4 acc = make_float4(0.f, 0.f, 0.f, 0.f);
    int c = 0;
    float v = 0.f;
    if (i < e) { c = cols[i]; v = vals[i]; }
    while (i < e) {
        int cn = 0;
        float vn = 0.f;
        if (i + 1 < e) { cn = cols[i + 1]; vn = vals[i + 1]; }
        ushort4 u = *(const ushort4*)&in[(size_t)c * 256 + colo];
        acc.x += v * bf2f(u.x);
        acc.y += v * bf2f(u.y);
        acc.z += v * bf2f(u.z);
        acc.w += v * bf2f(u.w);
        c = cn; v = vn; ++i;
    }
    acc.x = fmaxf(acc.x, 0.f); acc.y = fmaxf(acc.y, 0.f);
    acc.z = fmaxf(acc.z, 0.f); acc.w = fmaxf(acc.w, 0.f);
    *(ushort4*)&out[(size_t)row * 256 + colo] =
        make_ushort4(f2bf(acc.x), f2bf(acc.y), f2bf(acc.z), f2bf(acc.w));
}

// ---------------- final SpMM (D=128) + bias + mu/logvar split + Zh + out6 ----------------
// U row r = [mu0_r@dW (64) | logvar0_r@dW (64)] pre-bias (dense_W folded upstream).
// Wave per row; lane owns 2 cols. lanes 0-31 -> mu (+Zh bf16, + smu for out6);
// lanes 32-63 -> logvar. out6 = smu @ dense1_W + b computed per-wave from LDS.
__global__ __launch_bounds__(256) void k_spmm_fin(const int* __restrict__ offs,
                                                  const int* __restrict__ cols,
                                                  const float* __restrict__ vals,
                                                  const ushort* __restrict__ U,
                                                  const float* __restrict__ bias,  // dense_b[64]
                                                  const float* __restrict__ W6,    // dense1_W[64][6]
                                                  const float* __restrict__ b6,    // dense1_b[6]
                                                  float* __restrict__ mu,
                                                  float* __restrict__ logvar,
                                                  ushort* __restrict__ Zh,
                                                  float* __restrict__ out6) {
    __shared__ float smu[4][64];
    __shared__ float sW6[384];
    int t = threadIdx.x;
    for (int i = t; i < 384; i += 256) sW6[i] = W6[i];
    int w = t >> 6, lane = t & 63;
    int row = blockIdx.x * 4 + w;
    int colo = lane * 2;  // 0..126
    int i = offs[row], e = offs[row + 1];
    float2 acc = make_float2(0.f, 0.f);
    int c = 0;
    float v = 0.f;
    if (i < e) { c = cols[i]; v = vals[i]; }
    while (i < e) {
        int cn = 0;
        float vn = 0.f;
        if (i + 1 < e) { cn = cols[i + 1]; vn = vals[i + 1]; }
        ushort2 u = *(const ushort2*)&U[(size_t)c * 128 + colo];
        acc.x += v * bf2f(u.x);
        acc.y += v * bf2f(u.y);
        c = cn; v = vn; ++i;
    }
    int bc = colo & 63;
    acc.x += bias[bc];
    acc.y += bias[bc + 1];
    if (lane < 32) {
        *(float2*)&mu[(size_t)row * 64 + colo] = acc;
        ushort2 h;
        h.x = f2bf(acc.x);
        h.y = f2bf(acc.y);
        *(ushort2*)&Zh[(size_t)row * 64 + colo] = h;
        smu[w][colo] = acc.x;
        smu[w][colo + 1] = acc.y;
    } else {
        *(float2*)&logvar[(size_t)row * 64 + (colo - 64)] = acc;
    }
    __syncthreads();
    if (lane < 6) {
        float a6 = b6[lane];
        for (int k = 0; k < 64; k++) a6 += smu[w][k] * sW6[k * 6 + lane];
        out6[(size_t)row * 6 + lane] = a6;
    }
}

// ---------------- adj_rec = Z @ Z^T via bf16 MFMA ----------------
// Symmetric output: store transposed (C^T = C) so rg indexes consecutive addresses
// -> f32x4 stores, 16 store instrs/thread instead of 64.
__global__ __launch_bounds__(256) void k_zzt_mfma(const ushort* __restrict__ Zh,
                                                  float* __restrict__ C) {
    int t = threadIdx.x;
    int lane = t & 63;
    int w = t >> 6;  // wave 0..3
    int I = blockIdx.y * 128 + (w >> 1) * 64;
    int J = blockIdx.x * 128 + (w & 1) * 64;
    int r = lane & 15;
    int koff = (lane >> 4) * 8;

    short8 a[4][2], b[4][2];
#pragma unroll
    for (int m = 0; m < 4; m++) {
#pragma unroll
        for (int kk = 0; kk < 2; kk++) {
            a[m][kk] = *(const short8*)(Zh + (size_t)(I + m * 16 + r) * 64 + kk * 32 + koff);
            b[m][kk] = *(const short8*)(Zh + (size_t)(J + m * 16 + r) * 64 + kk * 32 + koff);
        }
    }
    f32x4 acc[4][4];
#pragma unroll
    for (int m = 0; m < 4; m++)
#pragma unroll
        for (int n = 0; n < 4; n++) acc[m][n] = (f32x4){0.f, 0.f, 0.f, 0.f};

#pragma unroll
    for (int kk = 0; kk < 2; kk++)
#pragma unroll
        for (int m = 0; m < 4; m++)
#pragma unroll
            for (int n = 0; n < 4; n++)
                acc[m][n] = __builtin_amdgcn_mfma_f32_16x16x32_bf16(a[m][kk], b[n][kk],
                                                                    acc[m][n], 0, 0, 0);

    int crow = (lane >> 4) * 4;
    int ccol = lane & 15;
#pragma unroll
    for (int m = 0; m < 4; m++)
#pragma unroll
        for (int n = 0; n < 4; n++) {
            size_t orow = (size_t)(J + n * 16 + ccol);
            *(f32x4*)&C[orow * 8192 + I + m * 16 + crow] = acc[m][n];
        }
}

extern "C" void kernel_launch(void* const* d_in, const int* in_sizes, int n_in,
                              void* d_out, int out_size, void* d_ws, size_t ws_size,
                              hipStream_t stream) {
    const float* x        = (const float*)d_in[0];
    const int*   adj_rows = (const int*)d_in[1];
    const int*   adj_cols = (const int*)d_in[2];
    const float* adj_vals = (const float*)d_in[3];
    const float* W1       = (const float*)d_in[4];
    const float* W2       = (const float*)d_in[5];
    const float* W3       = (const float*)d_in[6];
    const float* dense_W  = (const float*)d_in[7];
    const float* dense_b  = (const float*)d_in[8];
    const float* dense1_W = (const float*)d_in[9];
    const float* dense1_b = (const float*)d_in[10];

    // workspace layout (all chunks 16B-aligned)
    char* p = (char*)d_ws;
    int* counts   = (int*)p;    p += 8192 * 4;
    int* cursor   = (int*)p;    p += 8192 * 4;
    int* offs     = (int*)p;    p += 8224 * 4;                // 8193 used, padded
    int* scol     = (int*)p;    p += (size_t)N_EDGES * 4;
    float* sval   = (float*)p;  p += (size_t)N_EDGES * 4;
    ushort* xh    = (ushort*)p; p += (size_t)8192 * 512 * 2;  // x bf16
    ushort* W1t   = (ushort*)p; p += (size_t)256 * 512 * 2;   // W1^T bf16
    ushort* W23dt = (ushort*)p; p += (size_t)128 * 256 * 2;   // ([W2|W3] folded with dW)^T bf16
    ushort* XW1h  = (ushort*)p; p += (size_t)8192 * 256 * 2;  // x@W1 bf16
    ushort* Hidh  = (ushort*)p; p += (size_t)8192 * 256 * 2;  // hidden1 bf16
    ushort* Uh    = (ushort*)p; p += (size_t)8192 * 128 * 2;  // hidden1@W23d bf16
    ushort* Zh    = (ushort*)p; p += (size_t)8192 * 64 * 2;   // mu bf16

    // output layout: adj_rec [8192x8192], out6 [8192x6], mu [8192x64], logvar [8192x64]
    float* out     = (float*)d_out;
    float* adj_rec = out;
    float* out6    = out + (size_t)8192 * 8192;
    float* mu      = out6 + (size_t)8192 * 6;
    float* logvar  = mu + (size_t)8192 * 64;

    hipMemsetAsync(counts, 0, 2 * 8192 * 4, stream);  // counts + cursor
    // hist + x/W1 converts + dense_W fold, one launch
    k_prep<<<5760, 256, 0, stream>>>(adj_rows, counts, x, xh, W1, W1t, W2, W3,
                                     dense_W, W23dt);
    k_scan<<<1, 1024, 0, stream>>>(counts, offs);
    k_scatter<<<N_EDGES / 256, 256, 0, stream>>>(adj_rows, adj_cols, adj_vals, offs, cursor,
                                                 scol, sval);

    // XW1 = x @ W1  (bf16 MFMA, M=8192 K=512 N=256)
    k_gemm_mfma<<<dim3(4, 64), 128, 0, stream>>>(xh, W1t, XW1h, 512, 256);
    // hidden1 = relu(spmm(XW1))  -> bf16
    k_spmm_v2<<<2048, 256, 0, stream>>>(offs, scol, sval, XW1h, Hidh);
    // U = hidden1 @ W23d  (bf16 MFMA, K=256, N=128; dense_W pre-folded)
    k_gemm_mfma<<<dim3(2, 64), 128, 0, stream>>>(Hidh, W23dt, Uh, 256, 128);
    // [mu | logvar] = spmm(U) + dense_b ; Zh + out6 fused
    k_spmm_fin<<<2048, 256, 0, stream>>>(offs, scol, sval, Uh, dense_b, dense1_W, dense1_b,
                                         mu, logvar, Zh, out6);
    // adj_rec = mu @ mu^T (bf16 MFMA, fp32 accumulate, symmetric transposed store)
    k_zzt_mfma<<<dim3(64, 64), 256, 0, stream>>>(Zh, adj_rec);
}

// Round 5
// 428.517 us; speedup vs baseline: 1.0445x; 1.0445x over previous
//
#include <hip/hip_runtime.h>
#include <hip/hip_bf16.h>

#define N_NODES 8192
#define N_EDGES 262144
// F_IN=512, H1=256, H2=128 (x2 fused), H3=64, OUT6=6

typedef __attribute__((ext_vector_type(8))) short short8;
typedef __attribute__((ext_vector_type(4))) float f32x4;

__device__ __forceinline__ unsigned short f2bf(float f) {
    unsigned int u = __float_as_uint(f);
    u = (u + 0x7fffu + ((u >> 16) & 1u)) >> 16;  // RNE
    return (unsigned short)u;
}
__device__ __forceinline__ float bf2f(unsigned short h) {
    return __uint_as_float((unsigned int)h << 16);
}

// ---------------- CSR build ----------------
__global__ void k_scan(const int* __restrict__ counts, int* __restrict__ offs) {
    __shared__ int part[1024];
    int t = threadIdx.x;
    int base = t * 8;
    int loc[8];
    int s = 0;
#pragma unroll
    for (int i = 0; i < 8; i++) { loc[i] = s; s += counts[base + i]; }
    part[t] = s;
    __syncthreads();
    for (int off = 1; off < 1024; off <<= 1) {
        int v = (t >= off) ? part[t - off] : 0;
        __syncthreads();
        part[t] += v;
        __syncthreads();
    }
    int prev = (t == 0) ? 0 : part[t - 1];
#pragma unroll
    for (int i = 0; i < 8; i++) offs[base + i] = prev + loc[i];
    if (t == 1023) offs[N_NODES] = part[1023];
}

__global__ void k_scatter(const int* __restrict__ rows, const int* __restrict__ colsIn,
                          const float* __restrict__ valsIn, const int* __restrict__ offs,
                          int* __restrict__ cursor, int* __restrict__ colsOut,
                          float* __restrict__ valsOut) {
    int e = blockIdx.x * 256 + threadIdx.x;
    if (e >= N_EDGES) return;
    int r = rows[e];
    int p = atomicAdd(&cursor[r], 1);
    int idx = offs[r] + p;
    colsOut[idx] = colsIn[e];
    valsOut[idx] = valsIn[e];
}

// ---------------- fused prep: hist + converts + weight folds ----------------
// blocks [0,1024): hist; [1024,5120): x->bf16; [5120,5632): W1^T bf16;
// [5632,5760): W23dt = ([W2|W3] folded with dense_W)^T bf16 [128][256]
__global__ void k_prep(const int* __restrict__ rows, int* __restrict__ counts,
                       const float* __restrict__ x, ushort* __restrict__ xh,
                       const float* __restrict__ W1, ushort* __restrict__ W1t,
                       const float* __restrict__ W2, const float* __restrict__ W3,
                       const float* __restrict__ dW, ushort* __restrict__ W23dt) {
    int b = blockIdx.x, t = threadIdx.x;
    if (b < 1024) {
        atomicAdd(&counts[rows[b * 256 + t]], 1);
    } else if (b < 5120) {
        int i = (b - 1024) * 256 + t;  // over 1048576 float4
        float4 v = ((const float4*)x)[i];
        ((ushort4*)xh)[i] = make_ushort4(f2bf(v.x), f2bf(v.y), f2bf(v.z), f2bf(v.w));
    } else if (b < 5632) {
        int i = (b - 5120) * 256 + t;  // over 131072, i = k*256+n
        int k = i >> 8, n = i & 255;
        W1t[n * 512 + k] = f2bf(W1[i]);
    } else {
        // W23dt[n][k] = sum_j Wsrc[k][j] * dW[j][n&63], fp32 accumulate
        int i = (b - 5632) * 256 + t;  // over 32768, i = n*256+k
        int n = i >> 8, k = i & 255;
        const float* src = (n < 64) ? W2 : W3;
        int nn = n & 63;
        float acc = 0.f;
        for (int j = 0; j < 128; j++)
            acc += src[k * 128 + j] * dW[j * 64 + nn];
        W23dt[i] = f2bf(acc);
    }
}

// ---------------- bf16 MFMA GEMM: C[M,ldc] = A[M,K] @ Bt[N,K]^T, bf16 out ----------------
// block = 128 thr = 2 waves stacked on M; block tile 128x64; wave tile 64x64.
__global__ __launch_bounds__(128) void k_gemm_mfma(const ushort* __restrict__ A,
                                                   const ushort* __restrict__ Bt,
                                                   ushort* __restrict__ C,
                                                   int K, int ldc) {
    int t = threadIdx.x;
    int lane = t & 63;
    int w = t >> 6;
    int I = blockIdx.y * 128 + w * 64;
    int J = blockIdx.x * 64;
    int r = lane & 15;
    int koff = (lane >> 4) * 8;
    const ushort* Ab = A + (size_t)(I + r) * K + koff;
    const ushort* Bb = Bt + (size_t)(J + r) * K + koff;
    size_t rs = (size_t)16 * K;

    short8 a0[4], b0[4], a1[4], b1[4];
#pragma unroll
    for (int m = 0; m < 4; m++) {
        a0[m] = *(const short8*)(Ab + m * rs);
        b0[m] = *(const short8*)(Bb + m * rs);
    }
    f32x4 acc[4][4];
#pragma unroll
    for (int m = 0; m < 4; m++)
#pragma unroll
        for (int n = 0; n < 4; n++) acc[m][n] = (f32x4){0.f, 0.f, 0.f, 0.f};

    int nk = K >> 5;  // K=512 -> 16, K=256 -> 8 (even)
    for (int kt = 0; kt < nk; kt += 2) {
        int o1 = (kt + 1) << 5;
#pragma unroll
        for (int m = 0; m < 4; m++) {
            a1[m] = *(const short8*)(Ab + m * rs + o1);
            b1[m] = *(const short8*)(Bb + m * rs + o1);
        }
#pragma unroll
        for (int m = 0; m < 4; m++)
#pragma unroll
            for (int n = 0; n < 4; n++)
                acc[m][n] = __builtin_amdgcn_mfma_f32_16x16x32_bf16(a0[m], b0[n], acc[m][n], 0, 0, 0);
        if (kt + 2 < nk) {
            int o2 = (kt + 2) << 5;
#pragma unroll
            for (int m = 0; m < 4; m++) {
                a0[m] = *(const short8*)(Ab + m * rs + o2);
                b0[m] = *(const short8*)(Bb + m * rs + o2);
            }
        }
#pragma unroll
        for (int m = 0; m < 4; m++)
#pragma unroll
            for (int n = 0; n < 4; n++)
                acc[m][n] = __builtin_amdgcn_mfma_f32_16x16x32_bf16(a1[m], b1[n], acc[m][n], 0, 0, 0);
    }

    // C/D layout: col = lane&15, row = (lane>>4)*4 + reg   [m89-verified]
    int crow = (lane >> 4) * 4;
    int ccol = lane & 15;
#pragma unroll
    for (int m = 0; m < 4; m++)
#pragma unroll
        for (int rg = 0; rg < 4; rg++) {
            size_t row = (size_t)(I + m * 16 + crow + rg);
#pragma unroll
            for (int n = 0; n < 4; n++)
                C[row * ldc + J + n * 16 + ccol] = f2bf(acc[m][n][rg]);
        }
}

// ---------------- SpMM (CSR), D=256 bf16 in/out, relu: one row per WAVE ----------------
__global__ __launch_bounds__(256) void k_spmm_v2(const int* __restrict__ offs,
                                                 const int* __restrict__ cols,
                                                 const float* __restrict__ vals,
                                                 const ushort* __restrict__ in,
                                                 ushort* __restrict__ out) {
    int w = threadIdx.x >> 6;
    int lane = threadIdx.x & 63;
    int row = blockIdx.x * 4 + w;
    int colo = lane * 4;
    int i = offs[row], e = offs[row + 1];
    float4 acc = make_float4(0.f, 0.f, 0.f, 0.f);
    int c = 0;
    float v = 0.f;
    if (i < e) { c = cols[i]; v = vals[i]; }
    while (i < e) {
        int cn = 0;
        float vn = 0.f;
        if (i + 1 < e) { cn = cols[i + 1]; vn = vals[i + 1]; }
        ushort4 u = *(const ushort4*)&in[(size_t)c * 256 + colo];
        acc.x += v * bf2f(u.x);
        acc.y += v * bf2f(u.y);
        acc.z += v * bf2f(u.z);
        acc.w += v * bf2f(u.w);
        c = cn; v = vn; ++i;
    }
    acc.x = fmaxf(acc.x, 0.f); acc.y = fmaxf(acc.y, 0.f);
    acc.z = fmaxf(acc.z, 0.f); acc.w = fmaxf(acc.w, 0.f);
    *(ushort4*)&out[(size_t)row * 256 + colo] =
        make_ushort4(f2bf(acc.x), f2bf(acc.y), f2bf(acc.z), f2bf(acc.w));
}

// ---------------- final SpMM (D=128) + bias + mu/logvar split + Zh + out6 ----------------
// U row r = [mu0_r@dW (64) | logvar0_r@dW (64)] pre-bias (dense_W folded upstream).
// Wave per row; lane owns 2 cols. lanes 0-31 -> mu (+Zh bf16, + smu for out6);
// lanes 32-63 -> logvar. out6 = smu @ dense1_W + b computed per-wave from LDS.
__global__ __launch_bounds__(256) void k_spmm_fin(const int* __restrict__ offs,
                                                  const int* __restrict__ cols,
                                                  const float* __restrict__ vals,
                                                  const ushort* __restrict__ U,
                                                  const float* __restrict__ bias,  // dense_b[64]
                                                  const float* __restrict__ W6,    // dense1_W[64][6]
                                                  const float* __restrict__ b6,    // dense1_b[6]
                                                  float* __restrict__ mu,
                                                  float* __restrict__ logvar,
                                                  ushort* __restrict__ Zh,
                                                  float* __restrict__ out6) {
    __shared__ float smu[4][64];
    __shared__ float sW6[384];
    int t = threadIdx.x;
    for (int i = t; i < 384; i += 256) sW6[i] = W6[i];
    int w = t >> 6, lane = t & 63;
    int row = blockIdx.x * 4 + w;
    int colo = lane * 2;  // 0..126
    int i = offs[row], e = offs[row + 1];
    float2 acc = make_float2(0.f, 0.f);
    int c = 0;
    float v = 0.f;
    if (i < e) { c = cols[i]; v = vals[i]; }
    while (i < e) {
        int cn = 0;
        float vn = 0.f;
        if (i + 1 < e) { cn = cols[i + 1]; vn = vals[i + 1]; }
        ushort2 u = *(const ushort2*)&U[(size_t)c * 128 + colo];
        acc.x += v * bf2f(u.x);
        acc.y += v * bf2f(u.y);
        c = cn; v = vn; ++i;
    }
    int bc = colo & 63;
    acc.x += bias[bc];
    acc.y += bias[bc + 1];
    if (lane < 32) {
        *(float2*)&mu[(size_t)row * 64 + colo] = acc;
        ushort2 h;
        h.x = f2bf(acc.x);
        h.y = f2bf(acc.y);
        *(ushort2*)&Zh[(size_t)row * 64 + colo] = h;
        smu[w][colo] = acc.x;
        smu[w][colo + 1] = acc.y;
    } else {
        *(float2*)&logvar[(size_t)row * 64 + (colo - 64)] = acc;
    }
    __syncthreads();
    if (lane < 6) {
        float a6 = b6[lane];
        for (int k = 0; k < 64; k++) a6 += smu[w][k] * sW6[k * 6 + lane];
        out6[(size_t)row * 6 + lane] = a6;
    }
}

// ---------------- adj_rec = Z @ Z^T via bf16 MFMA ----------------
// Round-3 store restored: scalar stores, 4 rows x 64B-contiguous segments per
// wave-instruction (HBM-granule aligned). Transposed f32x4 store regressed +29us
// (64 scattered 16B segments/instr -> write amplification). zzt is write-BW-bound.
__global__ __launch_bounds__(256) void k_zzt_mfma(const ushort* __restrict__ Zh,
                                                  float* __restrict__ C) {
    int t = threadIdx.x;
    int lane = t & 63;
    int w = t >> 6;  // wave 0..3
    int I = blockIdx.y * 128 + (w >> 1) * 64;
    int J = blockIdx.x * 128 + (w & 1) * 64;
    int r = lane & 15;
    int koff = (lane >> 4) * 8;

    short8 a[4][2], b[4][2];
#pragma unroll
    for (int m = 0; m < 4; m++) {
#pragma unroll
        for (int kk = 0; kk < 2; kk++) {
            a[m][kk] = *(const short8*)(Zh + (size_t)(I + m * 16 + r) * 64 + kk * 32 + koff);
            b[m][kk] = *(const short8*)(Zh + (size_t)(J + m * 16 + r) * 64 + kk * 32 + koff);
        }
    }
    f32x4 acc[4][4];
#pragma unroll
    for (int m = 0; m < 4; m++)
#pragma unroll
        for (int n = 0; n < 4; n++) acc[m][n] = (f32x4){0.f, 0.f, 0.f, 0.f};

#pragma unroll
    for (int kk = 0; kk < 2; kk++)
#pragma unroll
        for (int m = 0; m < 4; m++)
#pragma unroll
            for (int n = 0; n < 4; n++)
                acc[m][n] = __builtin_amdgcn_mfma_f32_16x16x32_bf16(a[m][kk], b[n][kk],
                                                                    acc[m][n], 0, 0, 0);

    int crow = (lane >> 4) * 4;
    int ccol = lane & 15;
#pragma unroll
    for (int m = 0; m < 4; m++)
#pragma unroll
        for (int rg = 0; rg < 4; rg++) {
            size_t row = (size_t)(I + m * 16 + crow + rg);
#pragma unroll
            for (int n = 0; n < 4; n++)
                C[row * 8192 + J + n * 16 + ccol] = acc[m][n][rg];
        }
}

extern "C" void kernel_launch(void* const* d_in, const int* in_sizes, int n_in,
                              void* d_out, int out_size, void* d_ws, size_t ws_size,
                              hipStream_t stream) {
    const float* x        = (const float*)d_in[0];
    const int*   adj_rows = (const int*)d_in[1];
    const int*   adj_cols = (const int*)d_in[2];
    const float* adj_vals = (const float*)d_in[3];
    const float* W1       = (const float*)d_in[4];
    const float* W2       = (const float*)d_in[5];
    const float* W3       = (const float*)d_in[6];
    const float* dense_W  = (const float*)d_in[7];
    const float* dense_b  = (const float*)d_in[8];
    const float* dense1_W = (const float*)d_in[9];
    const float* dense1_b = (const float*)d_in[10];

    // workspace layout (all chunks 16B-aligned)
    char* p = (char*)d_ws;
    int* counts   = (int*)p;    p += 8192 * 4;
    int* cursor   = (int*)p;    p += 8192 * 4;
    int* offs     = (int*)p;    p += 8224 * 4;                // 8193 used, padded
    int* scol     = (int*)p;    p += (size_t)N_EDGES * 4;
    float* sval   = (float*)p;  p += (size_t)N_EDGES * 4;
    ushort* xh    = (ushort*)p; p += (size_t)8192 * 512 * 2;  // x bf16
    ushort* W1t   = (ushort*)p; p += (size_t)256 * 512 * 2;   // W1^T bf16
    ushort* W23dt = (ushort*)p; p += (size_t)128 * 256 * 2;   // ([W2|W3] folded with dW)^T bf16
    ushort* XW1h  = (ushort*)p; p += (size_t)8192 * 256 * 2;  // x@W1 bf16
    ushort* Hidh  = (ushort*)p; p += (size_t)8192 * 256 * 2;  // hidden1 bf16
    ushort* Uh    = (ushort*)p; p += (size_t)8192 * 128 * 2;  // hidden1@W23d bf16
    ushort* Zh    = (ushort*)p; p += (size_t)8192 * 64 * 2;   // mu bf16

    // output layout: adj_rec [8192x8192], out6 [8192x6], mu [8192x64], logvar [8192x64]
    float* out     = (float*)d_out;
    float* adj_rec = out;
    float* out6    = out + (size_t)8192 * 8192;
    float* mu      = out6 + (size_t)8192 * 6;
    float* logvar  = mu + (size_t)8192 * 64;

    hipMemsetAsync(counts, 0, 2 * 8192 * 4, stream);  // counts + cursor
    // hist + x/W1 converts + dense_W fold, one launch
    k_prep<<<5760, 256, 0, stream>>>(adj_rows, counts, x, xh, W1, W1t, W2, W3,
                                     dense_W, W23dt);
    k_scan<<<1, 1024, 0, stream>>>(counts, offs);
    k_scatter<<<N_EDGES / 256, 256, 0, stream>>>(adj_rows, adj_cols, adj_vals, offs, cursor,
                                                 scol, sval);

    // XW1 = x @ W1  (bf16 MFMA, M=8192 K=512 N=256)
    k_gemm_mfma<<<dim3(4, 64), 128, 0, stream>>>(xh, W1t, XW1h, 512, 256);
    // hidden1 = relu(spmm(XW1))  -> bf16
    k_spmm_v2<<<2048, 256, 0, stream>>>(offs, scol, sval, XW1h, Hidh);
    // U = hidden1 @ W23d  (bf16 MFMA, K=256, N=128; dense_W pre-folded)
    k_gemm_mfma<<<dim3(2, 64), 128, 0, stream>>>(Hidh, W23dt, Uh, 256, 128);
    // [mu | logvar] = spmm(U) + dense_b ; Zh + out6 fused
    k_spmm_fin<<<2048, 256, 0, stream>>>(offs, scol, sval, Uh, dense_b, dense1_W, dense1_b,
                                         mu, logvar, Zh, out6);
    // adj_rec = mu @ mu^T (bf16 MFMA, fp32 accumulate, round-3 coalesced store)
    k_zzt_mfma<<<dim3(64, 64), 256, 0, stream>>>(Zh, adj_rec);
}